// Round 2
// baseline (201.152 us; speedup 1.0000x reference)
//
#include <hip/hip_runtime.h>
#include <cfloat>

// Problem constants (fixed by reference): B=4, N=M=8192, D=3, fp32.
#define BB    4
#define NN    8192
#define MM    8192
#define NPTS  (BB * NN)         // 32768 queries per direction
#define QT    8                 // queries per thread (register tile)
#define BLK   256
#define QB    (BLK * QT)        // 2048 queries per block
#define QBLKS (NPTS / QB)       // 16 query-blocks per direction
#define SEG   64                // target segments per batch (grid = 2*16*64 = 2048)
#define TSEG  (MM / SEG)        // 128 targets per block (2 KB LDS)

// Monotone float->uint mapping so uint atomicMin == float min (handles negatives).
__device__ __forceinline__ unsigned int fmap(float f) {
    unsigned int u = __float_as_uint(f);
    return (u & 0x80000000u) ? ~u : (u | 0x80000000u);
}
__device__ __forceinline__ float funmap(unsigned int u) {
    u = (u & 0x80000000u) ? (u & 0x7FFFFFFFu) : ~u;
    return __uint_as_float(u);
}

// Trivial init: mins = +inf (ordered-uint max), tickets = 0, out = 0.
// Workspace is re-poisoned between iterations, so this must run every time.
__global__ void chamfer_init(unsigned int* __restrict__ mins,
                             unsigned int* __restrict__ tickets,
                             float* __restrict__ out, int out_size) {
    int i = blockIdx.x * blockDim.x + threadIdx.x;       // 16384 threads
    ((uint4*)mins)[i] = make_uint4(~0u, ~0u, ~0u, ~0u);  // 65536 uints = 256 KB
    if (i < 2 * QBLKS) tickets[i] = 0u;                  // 32 group counters
    if (i < out_size) out[i] = 0.f;
}

// Each thread: QT=8 query points vs TSEG=128 targets staged in LDS.
// Tracks min_j( ||t||^2/2 - q.t ); final value = 2*(min + ||q||^2/2).
// Inner loop processes target PAIRS: 6 fma + 1 min3 = 3.5 VALU ops per pair.
// Reduction is FUSED: last segment-block per (dir,qblk) group (ticket) sums
// its group's 2048 queries (whose coords it already holds in registers) and
// atomicAdds to out — eliminates the separate reduce kernel + launch gap.
__global__ void __launch_bounds__(256, 8) chamfer_main(
        const float* __restrict__ gts, const float* __restrict__ preds,
        unsigned int* __restrict__ mins, unsigned int* __restrict__ tickets,
        float* __restrict__ out) {
    __shared__ float4 st[TSEG];
    __shared__ float red[4];
    __shared__ unsigned int done;

    int bid  = blockIdx.x;          // grid = 2048
    int dir  = bid >> 10;           // 1024 blocks per direction
    int rest = bid & 1023;
    int qblk = rest >> 6;           // 16 query-blocks per direction
    int seg  = rest & 63;           // 64 target segments
    int b    = qblk >> 2;           // 4 query-blocks per batch (uniform per block)

    const float* __restrict__ Q = dir ? preds : gts;
    const float* __restrict__ T = dir ? gts : preds;
    const float* __restrict__ tp = T + (size_t)(b * MM + seg * TSEG) * 3;

    // Stage this segment's targets from raw float3, computing w on the fly.
    if (threadIdx.x < TSEG) {
        int j = threadIdx.x;
        float x = tp[3*j + 0], y = tp[3*j + 1], z = tp[3*j + 2];
        st[j] = make_float4(x, y, z, 0.5f * (x*x + y*y + z*z));
    }

    int q0 = qblk * QB + threadIdx.x;            // query index within direction
    const float* __restrict__ qp = Q + (size_t)q0 * 3;
    float qx[QT], qy[QT], qz[QT], m[QT];
    #pragma unroll
    for (int k = 0; k < QT; ++k) {
        qx[k] = qp[3*(256*k) + 0];
        qy[k] = qp[3*(256*k) + 1];
        qz[k] = qp[3*(256*k) + 2];
        m[k]  = FLT_MAX;
    }
    __syncthreads();

    #pragma unroll 4
    for (int j = 0; j < TSEG; j += 2) {
        float4 t0 = st[j], t1 = st[j+1];         // broadcast ds_read_b128 x2
        #pragma unroll
        for (int k = 0; k < QT; ++k) {
            float s0 = fmaf(-qx[k], t0.x,
                       fmaf(-qy[k], t0.y,
                       fmaf(-qz[k], t0.z, t0.w)));
            float s1 = fmaf(-qx[k], t1.x,
                       fmaf(-qy[k], t1.y,
                       fmaf(-qz[k], t1.z, t1.w)));
            m[k] = fminf(fminf(m[k], s0), s1);   // fuses to v_min3_f32
        }
    }

    #pragma unroll
    for (int k = 0; k < QT; ++k)
        atomicMin(&mins[dir * NPTS + q0 + 256*k], fmap(m[k]));

    // --- fused reduction: last block of this (dir,qblk) group sums it ---
    __threadfence();                             // release our atomicMins
    if (threadIdx.x == 0)
        done = atomicAdd(&tickets[dir * QBLKS + qblk], 1u);
    __syncthreads();
    if (done != SEG - 1) return;

    __threadfence();                             // acquire others' atomicMins
    float val = 0.f;
    #pragma unroll
    for (int k = 0; k < QT; ++k) {
        // identity atomicMin = coherent read of the final minimum
        unsigned int u = atomicMin(&mins[dir * NPTS + q0 + 256*k], 0xFFFFFFFFu);
        // this block's own queries are still in registers
        val += 2.0f * (funmap(u)
                       + 0.5f * (qx[k]*qx[k] + qy[k]*qy[k] + qz[k]*qz[k]));
    }

    #pragma unroll
    for (int off = 32; off > 0; off >>= 1)
        val += __shfl_down(val, off, 64);
    int lane = threadIdx.x & 63;
    int w_id = threadIdx.x >> 6;
    if (lane == 0) red[w_id] = val;
    __syncthreads();
    if (threadIdx.x == 0)
        atomicAdd(out, red[0] + red[1] + red[2] + red[3]);
}

extern "C" void kernel_launch(void* const* d_in, const int* in_sizes, int n_in,
                              void* d_out, int out_size, void* d_ws, size_t ws_size,
                              hipStream_t stream) {
    const float* gts   = (const float*)d_in[0];
    const float* preds = (const float*)d_in[1];
    float* out = (float*)d_out;

    unsigned int* mins    = (unsigned int*)d_ws;                       // 256 KB
    unsigned int* tickets = (unsigned int*)((char*)d_ws + (size_t)2 * NPTS * 4);

    chamfer_init<<<64, 256, 0, stream>>>(mins, tickets, out, out_size);
    chamfer_main<<<2 * QBLKS * SEG, 256, 0, stream>>>(gts, preds, mins, tickets, out);
}

// Round 3
// 200.377 us; speedup vs baseline: 1.0039x; 1.0039x over previous
//
#include <hip/hip_runtime.h>
#include <cfloat>

// Problem constants (fixed by reference): B=4, N=M=8192, D=3, fp32.
#define BB    4
#define NN    8192
#define MM    8192
#define NPTS  (BB * NN)         // 32768 queries per direction
#define QT    4                 // queries per thread (register tile) — 20 persistent regs, no spill
#define BLK   256
#define QB    (BLK * QT)        // 1024 queries per block
#define QBLKS (NPTS / QB)       // 32 query-blocks per direction
#define SEG   32                // target segments per batch (grid = 2*32*32 = 2048)
#define TSEG  (MM / SEG)        // 256 targets per block (4 KB LDS)

// Monotone float->uint mapping so uint atomicMin == float min (handles negatives).
__device__ __forceinline__ unsigned int fmap(float f) {
    unsigned int u = __float_as_uint(f);
    return (u & 0x80000000u) ? ~u : (u | 0x80000000u);
}
__device__ __forceinline__ float funmap(unsigned int u) {
    u = (u & 0x80000000u) ? (u & 0x7FFFFFFFu) : ~u;
    return __uint_as_float(u);
}

// v_min3_f32 exists on gfx950 (ISA §3) but clang does NOT fuse fminf chains
// without fast-math (verified: VALU-busy time identical across rounds 0-2).
__device__ __forceinline__ float min3f(float a, float b, float c) {
    float d;
    asm("v_min3_f32 %0, %1, %2, %3" : "=v"(d) : "v"(a), "v"(b), "v"(c));
    return d;
}

// Trivial init: mins = +inf (ordered-uint max), tickets = 0, out = 0.
// Workspace is re-poisoned between iterations, so this must run every time.
__global__ void chamfer_init(unsigned int* __restrict__ mins,
                             unsigned int* __restrict__ tickets,
                             float* __restrict__ out, int out_size) {
    int i = blockIdx.x * blockDim.x + threadIdx.x;       // 16384 threads
    ((uint4*)mins)[i] = make_uint4(~0u, ~0u, ~0u, ~0u);  // 65536 uints = 256 KB
    if (i < 2 * QBLKS) tickets[i] = 0u;                  // 64 group counters
    if (i < out_size) out[i] = 0.f;
}

// Each thread: QT=4 query points vs TSEG=256 targets staged in LDS.
// Tracks min_j( ||t||^2/2 - q.t ); final value = 2*(min + ||q||^2/2).
// Inner loop: target PAIRS, 6 fma + 1 v_min3 = 3.5 VALU instr per pair.
// Fused reduction: last segment-block per (dir,qblk) group sums its group's
// 1024 queries (q coords RELOADED from global, so the hot loop's register
// allocation is not extended — round 2's spill bug) and atomicAdds to out.
__global__ void __launch_bounds__(256, 8) chamfer_main(
        const float* __restrict__ gts, const float* __restrict__ preds,
        unsigned int* __restrict__ mins, unsigned int* __restrict__ tickets,
        float* __restrict__ out) {
    __shared__ float4 st[TSEG];
    __shared__ float red[4];
    __shared__ unsigned int done;

    int bid  = blockIdx.x;          // grid = 2048
    int dir  = bid >> 10;           // 1024 blocks per direction
    int rest = bid & 1023;
    int qblk = rest >> 5;           // 32 query-blocks per direction
    int seg  = rest & 31;           // 32 target segments
    int b    = qblk >> 3;           // 8 query-blocks per batch (uniform per block)

    const float* __restrict__ Q = dir ? preds : gts;
    const float* __restrict__ T = dir ? gts : preds;
    const float* __restrict__ tp = T + (size_t)(b * MM + seg * TSEG) * 3;

    // Stage this segment's targets from raw float3, computing w on the fly.
    {
        int j = threadIdx.x;
        float x = tp[3*j + 0], y = tp[3*j + 1], z = tp[3*j + 2];
        st[j] = make_float4(x, y, z, 0.5f * (x*x + y*y + z*z));
    }

    int q0 = qblk * QB + threadIdx.x;            // query index within direction
    const float* __restrict__ qp = Q + (size_t)q0 * 3;
    float qx[QT], qy[QT], qz[QT], m[QT];
    #pragma unroll
    for (int k = 0; k < QT; ++k) {
        qx[k] = qp[3*(256*k) + 0];
        qy[k] = qp[3*(256*k) + 1];
        qz[k] = qp[3*(256*k) + 2];
        m[k]  = FLT_MAX;
    }
    __syncthreads();

    #pragma unroll 4
    for (int j = 0; j < TSEG; j += 2) {
        float4 t0 = st[j], t1 = st[j+1];         // broadcast ds_read_b128 x2
        #pragma unroll
        for (int k = 0; k < QT; ++k) {
            float s0 = fmaf(-qx[k], t0.x,
                       fmaf(-qy[k], t0.y,
                       fmaf(-qz[k], t0.z, t0.w)));
            float s1 = fmaf(-qx[k], t1.x,
                       fmaf(-qy[k], t1.y,
                       fmaf(-qz[k], t1.z, t1.w)));
            m[k] = min3f(m[k], s0, s1);          // forced v_min3_f32
        }
    }

    #pragma unroll
    for (int k = 0; k < QT; ++k)
        atomicMin(&mins[dir * NPTS + q0 + 256*k], fmap(m[k]));

    // --- fused reduction: last block of this (dir,qblk) group sums it ---
    __threadfence();                             // release our atomicMins
    if (threadIdx.x == 0)
        done = atomicAdd(&tickets[dir * QBLKS + qblk], 1u);
    __syncthreads();
    if (done != SEG - 1) return;

    __threadfence();                             // acquire others' atomicMins
    float val = 0.f;
    #pragma unroll
    for (int k = 0; k < QT; ++k) {
        // identity atomicMin = coherent read of the final minimum
        unsigned int u = atomicMin(&mins[dir * NPTS + q0 + 256*k], 0xFFFFFFFFu);
        // reload q coords (L2-hot); keeps hot-loop register liveness short
        float x = qp[3*(256*k) + 0];
        float y = qp[3*(256*k) + 1];
        float z = qp[3*(256*k) + 2];
        val += 2.0f * (funmap(u) + 0.5f * (x*x + y*y + z*z));
    }

    #pragma unroll
    for (int off = 32; off > 0; off >>= 1)
        val += __shfl_down(val, off, 64);
    int lane = threadIdx.x & 63;
    int w_id = threadIdx.x >> 6;
    if (lane == 0) red[w_id] = val;
    __syncthreads();
    if (threadIdx.x == 0)
        atomicAdd(out, red[0] + red[1] + red[2] + red[3]);
}

extern "C" void kernel_launch(void* const* d_in, const int* in_sizes, int n_in,
                              void* d_out, int out_size, void* d_ws, size_t ws_size,
                              hipStream_t stream) {
    const float* gts   = (const float*)d_in[0];
    const float* preds = (const float*)d_in[1];
    float* out = (float*)d_out;

    unsigned int* mins    = (unsigned int*)d_ws;                       // 256 KB
    unsigned int* tickets = (unsigned int*)((char*)d_ws + (size_t)2 * NPTS * 4);

    chamfer_init<<<64, 256, 0, stream>>>(mins, tickets, out, out_size);
    chamfer_main<<<2 * QBLKS * SEG, 256, 0, stream>>>(gts, preds, mins, tickets, out);
}

// Round 4
// 97.156 us; speedup vs baseline: 2.0704x; 2.0624x over previous
//
#include <hip/hip_runtime.h>
#include <cfloat>

// Problem constants (fixed by reference): B=4, N=M=8192, D=3, fp32.
#define BB    4
#define NN    8192
#define MM    8192
#define NPTS  (BB * NN)         // 32768 queries per direction
#define QT    4                 // queries per thread (register tile)
#define BLK   256
#define QB    (BLK * QT)        // 1024 queries per block
#define QBLKS (NPTS / QB)       // 32 query-blocks per direction
#define SEG   32                // target segments per batch (grid = 2*32*32 = 2048)
#define TSEG  (MM / SEG)        // 256 targets per block (4 KB LDS)

// Monotone float->uint mapping so uint atomicMin == float min (handles negatives).
__device__ __forceinline__ unsigned int fmap(float f) {
    unsigned int u = __float_as_uint(f);
    return (u & 0x80000000u) ? ~u : (u | 0x80000000u);
}
__device__ __forceinline__ float funmap(unsigned int u) {
    u = (u & 0x80000000u) ? (u & 0x7FFFFFFFu) : ~u;
    return __uint_as_float(u);
}

// v_min3_f32 exists on gfx950 (ISA §3) but clang does NOT fuse fminf chains
// without fast-math.
__device__ __forceinline__ float min3f(float a, float b, float c) {
    float d;
    asm("v_min3_f32 %0, %1, %2, %3" : "=v"(d) : "v"(a), "v"(b), "v"(c));
    return d;
}

// Trivial init: mins = +inf (ordered-uint max), tickets = 0, out = 0.
// Workspace is re-poisoned between iterations, so this must run every time.
__global__ void chamfer_init(unsigned int* __restrict__ mins,
                             unsigned int* __restrict__ tickets,
                             float* __restrict__ out, int out_size) {
    int i = blockIdx.x * blockDim.x + threadIdx.x;       // 16384 threads
    ((uint4*)mins)[i] = make_uint4(~0u, ~0u, ~0u, ~0u);  // 65536 uints = 256 KB
    if (i < 2 * QBLKS) tickets[i] = 0u;                  // 64 group counters
    if (i < out_size) out[i] = 0.f;
}

// Each thread: QT=4 query points vs TSEG=256 targets staged in LDS.
// Tracks min_j( ||t||^2/2 - q.t ); final value = 2*(min + ||q||^2/2).
// Inner loop: target PAIRS, 6 fma + 1 v_min3 = 3.5 VALU instr per pair.
//
// Fused reduction WITHOUT __threadfence (rounds 2-3 lesson: __threadfence on
// gfx950 = buffer_wbl2/buffer_inv sc1 — an L2 writeback+invalidate per call;
// 2048 blocks x 2 fences cost ~115 us). All cross-block traffic here is
// device-scope atomic RMWs executing at the coherent point, so ordering only
// needs: my block's atomicMins COMPLETE before my ticket increment. That is
// s_waitcnt vmcnt(0) + __syncthreads() (barrier drains all waves' vmcnt).
__global__ void __launch_bounds__(256, 8) chamfer_main(
        const float* __restrict__ gts, const float* __restrict__ preds,
        unsigned int* __restrict__ mins, unsigned int* __restrict__ tickets,
        float* __restrict__ out) {
    __shared__ float4 st[TSEG];
    __shared__ float red[4];
    __shared__ unsigned int done;

    int bid  = blockIdx.x;          // grid = 2048
    int dir  = bid >> 10;           // 1024 blocks per direction
    int rest = bid & 1023;
    int qblk = rest >> 5;           // 32 query-blocks per direction
    int seg  = rest & 31;           // 32 target segments
    int b    = qblk >> 3;           // 8 query-blocks per batch (uniform per block)

    const float* __restrict__ Q = dir ? preds : gts;
    const float* __restrict__ T = dir ? gts : preds;
    const float* __restrict__ tp = T + (size_t)(b * MM + seg * TSEG) * 3;

    // Stage this segment's targets from raw float3, computing w on the fly.
    {
        int j = threadIdx.x;
        float x = tp[3*j + 0], y = tp[3*j + 1], z = tp[3*j + 2];
        st[j] = make_float4(x, y, z, 0.5f * (x*x + y*y + z*z));
    }

    int q0 = qblk * QB + threadIdx.x;            // query index within direction
    const float* __restrict__ qp = Q + (size_t)q0 * 3;
    float qx[QT], qy[QT], qz[QT], m[QT];
    #pragma unroll
    for (int k = 0; k < QT; ++k) {
        qx[k] = qp[3*(256*k) + 0];
        qy[k] = qp[3*(256*k) + 1];
        qz[k] = qp[3*(256*k) + 2];
        m[k]  = FLT_MAX;
    }
    __syncthreads();

    #pragma unroll 4
    for (int j = 0; j < TSEG; j += 2) {
        float4 t0 = st[j], t1 = st[j+1];         // broadcast ds_read_b128 x2
        #pragma unroll
        for (int k = 0; k < QT; ++k) {
            float s0 = fmaf(-qx[k], t0.x,
                       fmaf(-qy[k], t0.y,
                       fmaf(-qz[k], t0.z, t0.w)));
            float s1 = fmaf(-qx[k], t1.x,
                       fmaf(-qy[k], t1.y,
                       fmaf(-qz[k], t1.z, t1.w)));
            m[k] = min3f(m[k], s0, s1);          // forced v_min3_f32
        }
    }

    #pragma unroll
    for (int k = 0; k < QT; ++k)
        atomicMin(&mins[dir * NPTS + q0 + 256*k], fmap(m[k]));

    // --- fused reduction: last block of this (dir,qblk) group sums it ---
    asm volatile("s_waitcnt vmcnt(0)" ::: "memory");  // my atomics complete
    __syncthreads();                                  // ... for ALL waves
    if (threadIdx.x == 0)
        done = atomicAdd(&tickets[dir * QBLKS + qblk], 1u);
    __syncthreads();
    if (done != SEG - 1) return;

    float val = 0.f;
    #pragma unroll
    for (int k = 0; k < QT; ++k) {
        // identity atomicMin = coherent read of the final minimum (RMW at
        // the coherent point — no cache-invalidate fence needed)
        unsigned int u = atomicMin(&mins[dir * NPTS + q0 + 256*k], 0xFFFFFFFFu);
        // reload q coords (L2-hot); keeps hot-loop register liveness short
        float x = qp[3*(256*k) + 0];
        float y = qp[3*(256*k) + 1];
        float z = qp[3*(256*k) + 2];
        val += 2.0f * (funmap(u) + 0.5f * (x*x + y*y + z*z));
    }

    #pragma unroll
    for (int off = 32; off > 0; off >>= 1)
        val += __shfl_down(val, off, 64);
    int lane = threadIdx.x & 63;
    int w_id = threadIdx.x >> 6;
    if (lane == 0) red[w_id] = val;
    __syncthreads();
    if (threadIdx.x == 0)
        atomicAdd(out, red[0] + red[1] + red[2] + red[3]);
}

extern "C" void kernel_launch(void* const* d_in, const int* in_sizes, int n_in,
                              void* d_out, int out_size, void* d_ws, size_t ws_size,
                              hipStream_t stream) {
    const float* gts   = (const float*)d_in[0];
    const float* preds = (const float*)d_in[1];
    float* out = (float*)d_out;

    unsigned int* mins    = (unsigned int*)d_ws;                       // 256 KB
    unsigned int* tickets = (unsigned int*)((char*)d_ws + (size_t)2 * NPTS * 4);

    chamfer_init<<<64, 256, 0, stream>>>(mins, tickets, out, out_size);
    chamfer_main<<<2 * QBLKS * SEG, 256, 0, stream>>>(gts, preds, mins, tickets, out);
}

// Round 5
// 95.464 us; speedup vs baseline: 2.1071x; 1.0177x over previous
//
#include <hip/hip_runtime.h>
#include <cfloat>

// Problem constants (fixed by reference): B=4, N=M=8192, D=3, fp32.
#define BB    4
#define NN    8192
#define MM    8192
#define NPTS  (BB * NN)         // 32768 queries per direction
#define QT    4                 // queries per thread (register tile)
#define BLK   256
#define QB    (BLK * QT)        // 1024 queries per block
#define QBLKS (NPTS / QB)       // 32 query-blocks per direction
#define SEG   32                // target segments per batch (grid = 2*32*32 = 2048)
#define TSEG  (MM / SEG)        // 256 targets per block (4 KB LDS)

// Monotone float->uint mapping so uint atomicMin == float min (handles negatives).
__device__ __forceinline__ unsigned int fmap(float f) {
    unsigned int u = __float_as_uint(f);
    return (u & 0x80000000u) ? ~u : (u | 0x80000000u);
}
__device__ __forceinline__ float funmap(unsigned int u) {
    u = (u & 0x80000000u) ? (u & 0x7FFFFFFFu) : ~u;
    return __uint_as_float(u);
}

// Accumulating 3-input min, TIED to the accumulator register.
// Round-4 lesson: "=v" output + separate inputs made the allocator give the
// result a fresh register and insert v_mov back into the loop-carried m[k]
// (7+1 = 8 instr per 2 targets — exactly round 0's count; VALU-busy time was
// identical across rounds 0/1/4). "+v" pins result into m[k]'s register.
__device__ __forceinline__ void min3_acc(float& m, float a, float b) {
    asm("v_min3_f32 %0, %0, %1, %2" : "+v"(m) : "v"(a), "v"(b));
}

// Trivial init: mins = +inf (ordered-uint max), tickets = 0, out = 0.
// Workspace is re-poisoned between iterations, so this must run every time.
__global__ void chamfer_init(unsigned int* __restrict__ mins,
                             unsigned int* __restrict__ tickets,
                             float* __restrict__ out, int out_size) {
    int i = blockIdx.x * blockDim.x + threadIdx.x;       // 16384 threads
    ((uint4*)mins)[i] = make_uint4(~0u, ~0u, ~0u, ~0u);  // 65536 uints = 256 KB
    if (i < 2 * QBLKS) tickets[i] = 0u;                  // 64 group counters
    if (i < out_size) out[i] = 0.f;
}

// Each thread: QT=4 query points vs TSEG=256 targets staged in LDS.
// Tracks min_j( ||t||^2/2 - q.t ); final value = 2*(min + ||q||^2/2).
// Inner loop: target PAIRS, 6 fma + 1 tied v_min3 = 3.5 VALU instr per pair.
//
// Fused reduction WITHOUT __threadfence (round-3 lesson: __threadfence on
// gfx950 = buffer_wbl2/buffer_inv sc1 — L2 writeback+invalidate per call;
// 2048 blocks x 2 fences cost ~115 us). All cross-block traffic here is
// device-scope atomic RMWs executing at the coherent point, so ordering only
// needs: my block's atomicMins COMPLETE before my ticket increment. That is
// s_waitcnt vmcnt(0) + __syncthreads() (barrier drains all waves' vmcnt).
__global__ void __launch_bounds__(256, 8) chamfer_main(
        const float* __restrict__ gts, const float* __restrict__ preds,
        unsigned int* __restrict__ mins, unsigned int* __restrict__ tickets,
        float* __restrict__ out) {
    __shared__ float4 st[TSEG];
    __shared__ float red[4];
    __shared__ unsigned int done;

    int bid  = blockIdx.x;          // grid = 2048
    int dir  = bid >> 10;           // 1024 blocks per direction
    int rest = bid & 1023;
    int qblk = rest >> 5;           // 32 query-blocks per direction
    int seg  = rest & 31;           // 32 target segments
    int b    = qblk >> 3;           // 8 query-blocks per batch (uniform per block)

    const float* __restrict__ Q = dir ? preds : gts;
    const float* __restrict__ T = dir ? gts : preds;
    const float* __restrict__ tp = T + (size_t)(b * MM + seg * TSEG) * 3;

    // Stage this segment's targets from raw float3, computing w on the fly.
    {
        int j = threadIdx.x;
        float x = tp[3*j + 0], y = tp[3*j + 1], z = tp[3*j + 2];
        st[j] = make_float4(x, y, z, 0.5f * (x*x + y*y + z*z));
    }

    int q0 = qblk * QB + threadIdx.x;            // query index within direction
    const float* __restrict__ qp = Q + (size_t)q0 * 3;
    float qx[QT], qy[QT], qz[QT], m[QT];
    #pragma unroll
    for (int k = 0; k < QT; ++k) {
        qx[k] = qp[3*(256*k) + 0];
        qy[k] = qp[3*(256*k) + 1];
        qz[k] = qp[3*(256*k) + 2];
        m[k]  = FLT_MAX;
    }
    __syncthreads();

    #pragma unroll 4
    for (int j = 0; j < TSEG; j += 2) {
        float4 t0 = st[j], t1 = st[j+1];         // broadcast ds_read_b128 x2
        #pragma unroll
        for (int k = 0; k < QT; ++k) {
            float s0 = fmaf(-qx[k], t0.x,
                       fmaf(-qy[k], t0.y,
                       fmaf(-qz[k], t0.z, t0.w)));
            float s1 = fmaf(-qx[k], t1.x,
                       fmaf(-qy[k], t1.y,
                       fmaf(-qz[k], t1.z, t1.w)));
            min3_acc(m[k], s0, s1);              // tied v_min3_f32, no mov
        }
    }

    #pragma unroll
    for (int k = 0; k < QT; ++k)
        atomicMin(&mins[dir * NPTS + q0 + 256*k], fmap(m[k]));

    // --- fused reduction: last block of this (dir,qblk) group sums it ---
    asm volatile("s_waitcnt vmcnt(0)" ::: "memory");  // my atomics complete
    __syncthreads();                                  // ... for ALL waves
    if (threadIdx.x == 0)
        done = atomicAdd(&tickets[dir * QBLKS + qblk], 1u);
    __syncthreads();
    if (done != SEG - 1) return;

    float val = 0.f;
    #pragma unroll
    for (int k = 0; k < QT; ++k) {
        // identity atomicMin = coherent read of the final minimum (RMW at
        // the coherent point — no cache-invalidate fence needed)
        unsigned int u = atomicMin(&mins[dir * NPTS + q0 + 256*k], 0xFFFFFFFFu);
        // reload q coords (L2-hot); keeps hot-loop register liveness short
        float x = qp[3*(256*k) + 0];
        float y = qp[3*(256*k) + 1];
        float z = qp[3*(256*k) + 2];
        val += 2.0f * (funmap(u) + 0.5f * (x*x + y*y + z*z));
    }

    #pragma unroll
    for (int off = 32; off > 0; off >>= 1)
        val += __shfl_down(val, off, 64);
    int lane = threadIdx.x & 63;
    int w_id = threadIdx.x >> 6;
    if (lane == 0) red[w_id] = val;
    __syncthreads();
    if (threadIdx.x == 0)
        atomicAdd(out, red[0] + red[1] + red[2] + red[3]);
}

extern "C" void kernel_launch(void* const* d_in, const int* in_sizes, int n_in,
                              void* d_out, int out_size, void* d_ws, size_t ws_size,
                              hipStream_t stream) {
    const float* gts   = (const float*)d_in[0];
    const float* preds = (const float*)d_in[1];
    float* out = (float*)d_out;

    unsigned int* mins    = (unsigned int*)d_ws;                       // 256 KB
    unsigned int* tickets = (unsigned int*)((char*)d_ws + (size_t)2 * NPTS * 4);

    chamfer_init<<<64, 256, 0, stream>>>(mins, tickets, out, out_size);
    chamfer_main<<<2 * QBLKS * SEG, 256, 0, stream>>>(gts, preds, mins, tickets, out);
}